// Round 16
// baseline (91.724 us; speedup 1.0000x reference)
//
#include <hip/hip_runtime.h>

// DNA transport NEGF: per (b,e) invert A = (E*I - H) + i*diag(0.5*(gL+gR)),
// DOS = -Im tr(Gr), T = sum_ij gL_i gR_j |Gr_ij|^2, plus H scatter output.
//
// R16 DPP ELIMINATION (no DS in the hot loop): R10-R15 plateaued at ~105us
// with THREE co-limits: VALU ~40-64us, DS pipe ~60us (1/CU, shared by 4
// SIMDs -- why occupancy never mattered), latency at 2 waves/SIMD (reg
// granule {64,128,256}: no 3-wave tier, R13). Fix: 4 lanes/matrix (16
// matrices/wave, all 64 lanes active). Lane m owns cols j=4c+m (5 slots,
// triangular rows 0..4c+3, 60 complex as separate x/y FIXED registers:
// X(c,r)=v[20+2c(c+1)+r], Y=+60). Pivot-column broadcast via
// v_mov_b32_dpp quad_perm:[m*,m*,m*,m*] -- pure VALU, compile-time pattern
// per step, zero DS, near-zero serial latency. Updates = 4 scalar v_fma
// per row (sign-free: col_j[i] -= y_i * t_j for ALL i,j -- validated R10).
// Row k skipped in the sweep and set directly (PSET/POWN). Whole kernel is
// ONE asm block generated by assembler .macro/.rept/.set with v[expr]
// register indexing; outputs tv,dv only.
//
// y_i sources (M[i][k]): i<=k from owner's pivot col (slot k/4, lane k%4);
// i>k from col i's row k (symmetry, both unprocessed): slot i/4, lane i%4.
// Processed-col t_j = -y_j*p: y_j captured during sweep1 (masked cndmask).
//
// No pivoting: imag(x^* A x) > 0 for all leading blocks => pivots bounded
// below. Stable in fp32 (R0-R15: absmax <= 3.9e-3).

#define H_N   20
#define NE    100
#define T_OFF 0
#define D_OFF 102400
#define H_OFF 204800

__device__ __forceinline__ int triIdx(int i, int j) {  // i <= j, row-major triu
    return i * H_N - ((i * (i - 1)) >> 1) + (j - i);
}

// ---- assembler macro library (expanded by the integrated assembler) ----
// Symbols: KK step; CS=KK/4; MS=KK-4CS; OFS=2*CS*(CS+1); SRX/SRY dpp srcs;
// PP quad_perm pattern; II row; CC slot; OFC slot offset.
// Regs: v0:1 p(px,py); v2,v3 tmp; v4,v5 bcast; v6-v15 t pairs (t_c=v[6+2c])
// (also gam/l/r staging); v16,v17 tmp/totals; v18 tmp; X v20-79; Y v80-139.

#define NG_MACROS \
".macro NGBC45\n"                                                             \
".if PP==0\n"                                                                 \
" v_mov_b32_dpp v4, v[SRX] quad_perm:[0,0,0,0] row_mask:0xf bank_mask:0xf\n"  \
" v_mov_b32_dpp v5, v[SRY] quad_perm:[0,0,0,0] row_mask:0xf bank_mask:0xf\n"  \
".elseif PP==1\n"                                                             \
" v_mov_b32_dpp v4, v[SRX] quad_perm:[1,1,1,1] row_mask:0xf bank_mask:0xf\n"  \
" v_mov_b32_dpp v5, v[SRY] quad_perm:[1,1,1,1] row_mask:0xf bank_mask:0xf\n"  \
".elseif PP==2\n"                                                             \
" v_mov_b32_dpp v4, v[SRX] quad_perm:[2,2,2,2] row_mask:0xf bank_mask:0xf\n"  \
" v_mov_b32_dpp v5, v[SRY] quad_perm:[2,2,2,2] row_mask:0xf bank_mask:0xf\n"  \
".else\n"                                                                     \
" v_mov_b32_dpp v4, v[SRX] quad_perm:[3,3,3,3] row_mask:0xf bank_mask:0xf\n"  \
" v_mov_b32_dpp v5, v[SRY] quad_perm:[3,3,3,3] row_mask:0xf bank_mask:0xf\n"  \
".endif\n"                                                                    \
".endm\n"                                                                     \
".macro NGBC01\n"                                                             \
".if PP==0\n"                                                                 \
" v_mov_b32_dpp v0, v[SRX] quad_perm:[0,0,0,0] row_mask:0xf bank_mask:0xf\n"  \
" v_mov_b32_dpp v1, v[SRY] quad_perm:[0,0,0,0] row_mask:0xf bank_mask:0xf\n"  \
".elseif PP==1\n"                                                             \
" v_mov_b32_dpp v0, v[SRX] quad_perm:[1,1,1,1] row_mask:0xf bank_mask:0xf\n"  \
" v_mov_b32_dpp v1, v[SRY] quad_perm:[1,1,1,1] row_mask:0xf bank_mask:0xf\n"  \
".elseif PP==2\n"                                                             \
" v_mov_b32_dpp v0, v[SRX] quad_perm:[2,2,2,2] row_mask:0xf bank_mask:0xf\n"  \
" v_mov_b32_dpp v1, v[SRY] quad_perm:[2,2,2,2] row_mask:0xf bank_mask:0xf\n"  \
".else\n"                                                                     \
" v_mov_b32_dpp v0, v[SRX] quad_perm:[3,3,3,3] row_mask:0xf bank_mask:0xf\n"  \
" v_mov_b32_dpp v1, v[SRY] quad_perm:[3,3,3,3] row_mask:0xf bank_mask:0xf\n"  \
".endif\n"                                                                    \
".endm\n"

#define NG_STEP \
".macro NGSTEP\n"                                                             \
".set CS, KK/4\n"                                                             \
".set MS, KK-4*CS\n"                                                          \
".set OFS, 2*CS*(CS+1)\n"                                                     \
"s_nop 2\n"                                                                   \
/* pivot broadcast + complex reciprocal p = 1/M[k][k] (in v0:1) */            \
".set SRX, 20+OFS+KK\n.set SRY, 80+OFS+KK\n.set PP, MS\n"                     \
"NGBC01\n"                                                                    \
"v_mul_f32 v2, v0, v0\n"                                                      \
"v_fma_f32 v2, v1, v1, v2\n"                                                  \
"v_rcp_f32 v2, v2\n"                                                          \
"s_nop 1\n"                                                                   \
"v_mul_f32 v0, v0, v2\n"                                                      \
"v_mul_f32 v1, -v1, v2\n"                                                     \
/* sweep1: broadcast y_i (i<k) from owner, capture into t_{i/4} where j==i */ \
".if KK>0\n"                                                                  \
".set II, 0\n"                                                                \
".rept KK\n"                                                                  \
" .set SRX, 20+OFS+II\n .set SRY, 80+OFS+II\n .set PP, MS\n"                  \
" NGBC45\n"                                                                   \
" .set TC, II/4\n"                                                            \
" v_cmp_eq_u32 vcc, II-4*(II/4), %[vm]\n"                                     \
" v_cndmask_b32 v[6+2*TC], v[6+2*TC], v4, vcc\n"                              \
" v_cndmask_b32 v[7+2*TC], v[7+2*TC], v5, vcc\n"                              \
" .set II, II+1\n"                                                            \
".endr\n"                                                                     \
".endif\n"                                                                    \
/* t per slot: c<CS TN=cmul(-cap,p); c>CS TP=cmul(A_c[k],p); c==CS mixed */   \
".set CC, 0\n"                                                                \
".rept 5\n"                                                                   \
" .set OFC, 2*CC*(CC+1)\n"                                                    \
" .if CC < CS\n"                                                              \
"  v_mul_f32 v16, v[6+2*CC], v0\n"                                            \
"  v_mul_f32 v17, v[6+2*CC], v1\n"                                            \
"  v_fma_f32 v[6+2*CC], v[7+2*CC], v1, -v16\n"                                \
"  v_fma_f32 v[7+2*CC], -v[7+2*CC], v0, -v17\n"                               \
" .elseif CC > CS\n"                                                          \
"  v_mul_f32 v[6+2*CC], v[20+OFC+KK], v0\n"                                   \
"  v_fma_f32 v[6+2*CC], -v[80+OFC+KK], v1, v[6+2*CC]\n"                       \
"  v_mul_f32 v[7+2*CC], v[20+OFC+KK], v1\n"                                   \
"  v_fma_f32 v[7+2*CC], v[80+OFC+KK], v0, v[7+2*CC]\n"                        \
" .else\n"                                                                    \
"  v_mul_f32 v16, v[6+2*CC], v0\n"                                            \
"  v_mul_f32 v17, v[6+2*CC], v1\n"                                            \
"  v_fma_f32 v[6+2*CC], v[7+2*CC], v1, -v16\n"                                \
"  v_fma_f32 v[7+2*CC], -v[7+2*CC], v0, -v17\n"                               \
"  v_mul_f32 v16, v[20+OFC+KK], v0\n"                                         \
"  v_fma_f32 v16, -v[80+OFC+KK], v1, v16\n"                                   \
"  v_mul_f32 v17, v[20+OFC+KK], v1\n"                                         \
"  v_fma_f32 v17, v[80+OFC+KK], v0, v17\n"                                    \
"  v_cmp_lt_u32 vcc, MS, %[vm]\n"                                             \
"  v_cndmask_b32 v[6+2*CC], v[6+2*CC], v16, vcc\n"                            \
"  v_cndmask_b32 v[7+2*CC], v[7+2*CC], v17, vcc\n"                            \
"  v_add_f32 v18, 1.0, v0\n"                                                  \
"  v_cmp_eq_u32 vcc, MS, %[vm]\n"                                             \
"  v_cndmask_b32 v[6+2*CC], v[6+2*CC], v18, vcc\n"                            \
"  v_cndmask_b32 v[7+2*CC], v[7+2*CC], v1, vcc\n"                             \
" .endif\n"                                                                   \
" .set CC, CC+1\n"                                                            \
".endr\n"                                                                     \
/* sweep2: rows i != k: broadcast y_i then col_j[i] -= y_i * t_c */           \
".set II, 0\n"                                                                \
".rept 20\n"                                                                  \
" .if II != KK\n"                                                             \
"  .if II < KK\n"                                                             \
"   .set SRX, 20+OFS+II\n   .set SRY, 80+OFS+II\n   .set PP, MS\n"            \
"  .else\n"                                                                   \
"   .set C2, II/4\n"                                                          \
"   .set SRX, 20+2*C2*(C2+1)+KK\n   .set SRY, 80+2*C2*(C2+1)+KK\n"            \
"   .set PP, II-4*C2\n"                                                       \
"  .endif\n"                                                                  \
"  NGBC45\n"                                                                  \
"  .set CC, II/4\n"                                                           \
"  .rept 5-(II/4)\n"                                                          \
"   .set OFC, 2*CC*(CC+1)\n"                                                  \
"   v_fma_f32 v[20+OFC+II], -v4, v[6+2*CC], v[20+OFC+II]\n"                   \
"   v_fma_f32 v[20+OFC+II], v5, v[7+2*CC], v[20+OFC+II]\n"                    \
"   v_fma_f32 v[80+OFC+II], -v4, v[7+2*CC], v[80+OFC+II]\n"                   \
"   v_fma_f32 v[80+OFC+II], -v5, v[6+2*CC], v[80+OFC+II]\n"                   \
"   .set CC, CC+1\n"                                                          \
"  .endr\n"                                                                   \
" .endif\n"                                                                   \
" .set II, II+1\n"                                                            \
".endr\n"                                                                     \
/* row-k fix: slots c>CS: A_c[k]=t_c ; slot CS: owner p, others t */          \
".if CS<4\n"                                                                  \
" .set CC, CS+1\n"                                                            \
" .rept 4-CS\n"                                                               \
"  .set OFC, 2*CC*(CC+1)\n"                                                   \
"  v_mov_b32 v[20+OFC+KK], v[6+2*CC]\n"                                       \
"  v_mov_b32 v[80+OFC+KK], v[7+2*CC]\n"                                       \
"  .set CC, CC+1\n"                                                           \
" .endr\n"                                                                    \
".endif\n"                                                                    \
"v_cmp_eq_u32 vcc, MS, %[vm]\n"                                               \
"v_cndmask_b32 v[20+OFS+KK], v[6+2*CS], v0, vcc\n"                            \
"v_cndmask_b32 v[80+OFS+KK], v[7+2*CS], v1, vcc\n"                            \
".endm\n"

__global__ __launch_bounds__(256, 2)
void negf_all(const float* __restrict__ tri,
              const float* __restrict__ GL,
              const float* __restrict__ GR,
              float* __restrict__ out)
{
    // 4 independent waves/block; per-wave slice: [0,400) Hcm col-major,
    // [400,420) sgL, [420,440) sgR, pad to 448.
    __shared__ __align__(16) float lds[4][448];

    const int tid   = threadIdx.x;
    const int wid   = tid >> 6;
    const int lane  = tid & 63;
    const int w     = blockIdx.x * 4 + wid;   // wave unit: (b, chunk)
    const int b     = w / 7;
    const int chunk = w - b * 7;

    float* const Hcm = &lds[wid][0];
    float* const sgL = &lds[wid][400];
    float* const sgR = &lds[wid][420];

    // ---- per-wave staging of H (col-major) + gammas ----
    const float* triB = tri + b * 210;
    for (int u = lane; u < 400; u += 64) {
        int c = u / 20, r = u - c * 20;
        int lo = r < c ? r : c;
        int hi = r < c ? c : r;
        Hcm[u] = triB[triIdx(lo, hi)];
    }
    if (lane < H_N) { sgL[lane] = GL[b * H_N + lane]; sgR[lane] = GR[b * H_N + lane]; }
    asm volatile("s_waitcnt lgkmcnt(0)" ::: "memory");   // wave-coherent LDS

    // ---- H output (row-major, exact copy); one wave per b ----
    if (chunk == 0) {
        for (int u = lane; u < 400; u += 64) {
            int r = u / 20, c = u - r * 20;
            out[H_OFF + b * 400 + u] = Hcm[c * 20 + r];
        }
    }

    const int m  = lane & 3;                  // lane within matrix quad
    const int sg = lane >> 2;                 // matrix 0..15
    const int e  = chunk * 16 + sg;           // energy (may exceed 99: compute, don't store)
    const float E = fmaf((float)e, 6.0f / 99.0f, -3.0f);

    const int j0 = m, j1 = 4 + m, j2 = 8 + m, j3 = 12 + m, j4 = 16 + m;
    const float l0 = sgL[j0], l1 = sgL[j1], l2 = sgL[j2], l3 = sgL[j3], l4 = sgL[j4];
    const float r0 = sgR[j0], r1 = sgR[j1], r2 = sgR[j2], r3 = sgR[j3], r4 = sgR[j4];
    const float g0 = 0.5f * (l0 + r0), g1 = 0.5f * (l1 + r1), g2 = 0.5f * (l2 + r2);
    const float g3 = 0.5f * (l3 + r3), g4 = 0.5f * (l4 + r4);

    const unsigned ha  = (unsigned)(size_t)Hcm + 80u * (unsigned)m;  // col j=4c+m at +320c
    const unsigned vmu = (unsigned)m;
    float tv, dv;

    asm volatile(
        NG_MACROS
        NG_STEP
        "s_waitcnt lgkmcnt(0)\n"
        // ---- init: load cols (rows 0..4c+3 of col 4c+m), X=-h, Y=0 ----
        "ds_read_b128 v[20:23], %[ha] offset:0\n"
        "ds_read_b128 v[24:27], %[ha] offset:320\n"
        "ds_read_b128 v[28:31], %[ha] offset:336\n"
        "ds_read_b128 v[32:35], %[ha] offset:640\n"
        "ds_read_b128 v[36:39], %[ha] offset:656\n"
        "ds_read_b128 v[40:43], %[ha] offset:672\n"
        "ds_read_b128 v[44:47], %[ha] offset:960\n"
        "ds_read_b128 v[48:51], %[ha] offset:976\n"
        "ds_read_b128 v[52:55], %[ha] offset:992\n"
        "ds_read_b128 v[56:59], %[ha] offset:1008\n"
        "ds_read_b128 v[60:63], %[ha] offset:1280\n"
        "ds_read_b128 v[64:67], %[ha] offset:1296\n"
        "ds_read_b128 v[68:71], %[ha] offset:1312\n"
        "ds_read_b128 v[72:75], %[ha] offset:1328\n"
        "ds_read_b128 v[76:79], %[ha] offset:1344\n"
        "s_waitcnt lgkmcnt(0)\n"
        ".set NN, 0\n"
        ".rept 60\n"
        " v_xor_b32 v[20+NN], 0x80000000, v[20+NN]\n"
        " v_mov_b32 v[80+NN], 0\n"
        " .set NN, NN+1\n"
        ".endr\n"
        // gammas into v6..v10 for masked diag init
        "v_mov_b32 v6, %[g0]\n"
        "v_mov_b32 v7, %[g1]\n"
        "v_mov_b32 v8, %[g2]\n"
        "v_mov_b32 v9, %[g3]\n"
        "v_mov_b32 v10, %[g4]\n"
        // diag: X(c, 4c+m) += E ; Y(c, 4c+m) = gam_c  (masked per m)
        ".set CC, 0\n"
        ".rept 5\n"
        " .set OFC, 2*CC*(CC+1)\n"
        " .set MM, 0\n"
        " .rept 4\n"
        "  .set DR, 4*CC+MM\n"
        "  v_cmp_eq_u32 vcc, MM, %[vm]\n"
        "  v_cndmask_b32 v18, 0, %[E], vcc\n"
        "  v_add_f32 v[20+OFC+DR], v18, v[20+OFC+DR]\n"
        "  v_cndmask_b32 v[80+OFC+DR], v[80+OFC+DR], v[6+CC], vcc\n"
        "  .set MM, MM+1\n"
        " .endr\n"
        " .set CC, CC+1\n"
        ".endr\n"
        // ---- 20 elimination steps ----
        ".set KK, 0\n"
        ".rept 20\n"
        " NGSTEP\n"
        " .set KK, KK+1\n"
        ".endr\n"
        // ---- epilogue: tv = sum w_ij |G_ij|^2 (triangle), dv = sum Im G_jj ----
        "v_mov_b32 v6, %[l0]\n"
        "v_mov_b32 v7, %[l1]\n"
        "v_mov_b32 v8, %[l2]\n"
        "v_mov_b32 v9, %[l3]\n"
        "v_mov_b32 v10, %[l4]\n"
        "v_mov_b32 v11, %[r0]\n"
        "v_mov_b32 v12, %[r1]\n"
        "v_mov_b32 v13, %[r2]\n"
        "v_mov_b32 v14, %[r3]\n"
        "v_mov_b32 v15, %[r4]\n"
        "v_mov_b32 v16, 0\n"
        "v_mov_b32 v17, 0\n"
        "s_nop 2\n"
        ".set II, 0\n"
        ".rept 20\n"
        " .set SRX, 6+II/4\n"
        " .set SRY, 11+II/4\n"
        " .set PP, II-4*(II/4)\n"
        " NGBC45\n"                       // v4 = gL_i, v5 = gR_i (broadcast)
        " .set CC, II/4\n"
        " .rept 5-(II/4)\n"
        "  .set OFC, 2*CC*(CC+1)\n"
        "  v_mul_f32 v18, v[20+OFC+II], v[20+OFC+II]\n"
        "  v_fma_f32 v18, v[80+OFC+II], v[80+OFC+II], v18\n"
        "  v_mul_f32 v2, v4, v[11+CC]\n"  // gL_i * gR_j
        "  v_mul_f32 v3, v[6+CC], v5\n"   // gL_j * gR_i
        "  .if CC == II/4\n"
        "   v_cmp_le_u32 vcc, II-4*CC, %[vm]\n"
        "   v_cndmask_b32 v2, 0, v2, vcc\n"
        "   v_cmp_lt_u32 vcc, II-4*CC, %[vm]\n"
        "   v_cndmask_b32 v3, 0, v3, vcc\n"
        "  .endif\n"
        "  v_add_f32 v2, v2, v3\n"
        "  v_fma_f32 v16, v18, v2, v16\n"
        "  .if CC == II/4\n"
        "   v_cmp_eq_u32 vcc, II-4*CC, %[vm]\n"
        "   v_cndmask_b32 v18, 0, v[80+OFC+II], vcc\n"
        "   v_add_f32 v17, v17, v18\n"
        "  .endif\n"
        "  .set CC, CC+1\n"
        " .endr\n"
        " .set II, II+1\n"
        ".endr\n"
        "v_mov_b32 %[tv], v16\n"
        "v_mov_b32 %[dv], v17\n"
        : [tv]"=&v"(tv), [dv]"=&v"(dv)
        : [ha]"v"(ha), [vm]"v"(vmu), [E]"v"(E),
          [g0]"v"(g0), [g1]"v"(g1), [g2]"v"(g2), [g3]"v"(g3), [g4]"v"(g4),
          [l0]"v"(l0), [l1]"v"(l1), [l2]"v"(l2), [l3]"v"(l3), [l4]"v"(l4),
          [r0]"v"(r0), [r1]"v"(r1), [r2]"v"(r2), [r3]"v"(r3), [r4]"v"(r4)
        : "vcc", "memory",
          "v0","v1","v2","v3","v4","v5","v6","v7","v8","v9",
          "v10","v11","v12","v13","v14","v15","v16","v17","v18","v19",
          "v20","v21","v22","v23","v24","v25","v26","v27","v28","v29",
          "v30","v31","v32","v33","v34","v35","v36","v37","v38","v39",
          "v40","v41","v42","v43","v44","v45","v46","v47","v48","v49",
          "v50","v51","v52","v53","v54","v55","v56","v57","v58","v59",
          "v60","v61","v62","v63","v64","v65","v66","v67","v68","v69",
          "v70","v71","v72","v73","v74","v75","v76","v77","v78","v79",
          "v80","v81","v82","v83","v84","v85","v86","v87","v88","v89",
          "v90","v91","v92","v93","v94","v95","v96","v97","v98","v99",
          "v100","v101","v102","v103","v104","v105","v106","v107","v108","v109",
          "v110","v111","v112","v113","v114","v115","v116","v117","v118","v119",
          "v120","v121","v122","v123","v124","v125","v126","v127","v128","v129",
          "v130","v131","v132","v133","v134","v135","v136","v137","v138","v139");

    // ---- 4-lane reduce within each matrix quad, then store ----
    float tB = __shfl(tv, lane + 2, 64);
    float dB = __shfl(dv, lane + 2, 64);
    if (m < 2) { tv += tB; dv += dB; }
    tB = __shfl(tv, lane + 1, 64);
    dB = __shfl(dv, lane + 1, 64);
    if (m == 0) { tv += tB; dv += dB; }

    if (m == 0 && e < NE) {
        out[T_OFF + b * NE + e] = __log10f(fmaxf(tv, 1e-16f));
        out[D_OFF + b * NE + e] = __log10f(fmaxf(-dv, 1e-16f));
    }
}

extern "C" void kernel_launch(void* const* d_in, const int* in_sizes, int n_in,
                              void* d_out, int out_size, void* d_ws, size_t ws_size,
                              hipStream_t stream) {
    const float* tri = (const float*)d_in[0];
    const float* gL  = (const float*)d_in[1];
    const float* gR  = (const float*)d_in[2];
    float* out = (float*)d_out;
    negf_all<<<1792, 256, 0, stream>>>(tri, gL, gR, out);   // 1024 b x 7 chunks x 4 waves
}